// Round 12
// baseline (514.594 us; speedup 1.0000x reference)
//
#include <hip/hip_runtime.h>
#include <math.h>

#define S_LEN 4096
#define HID   2048
#define NH    16
#define HD    128
#define NKV   2048
#define KT    64
#define QBLK  256
#define NT    (NKV / KT)
// (1/sqrt(128)) * log2(e) -- folded into Q so QK^T lands in exp2 domain
#define QSCALE 0.12754103668587426f

typedef __attribute__((ext_vector_type(8))) _Float16 half8;
typedef __attribute__((ext_vector_type(4))) _Float16 half4;
typedef __attribute__((ext_vector_type(2))) __fp16 fp16x2;
typedef __attribute__((ext_vector_type(4))) float f32x4;
typedef __attribute__((ext_vector_type(16))) float f32x16;

#define GLB_AS __attribute__((address_space(1)))
#define LDS_AS __attribute__((address_space(3)))

__device__ __forceinline__ void gload16(const void* g, void* l) {
  __builtin_amdgcn_global_load_lds((GLB_AS const void*)g, (LDS_AS void*)l, 16, 0, 0);
}

__device__ __forceinline__ unsigned pkrtz(float a, float b) {
  union { fp16x2 h; unsigned u; } cv;
  cv.h = __builtin_amdgcn_cvt_pkrtz(a, b);
  return cv.u;
}

// ---------- index build ----------
__global__ void k_build_idx(const int* __restrict__ hmap, int* __restrict__ gidx) {
  int i = blockIdx.x * 256 + threadIdx.x;
  if (i < NKV) gidx[i] = hmap[2 * i];
}

// ---------- fused fp32 -> fp16 conversion for x, w_qkv, w_out ----------
#define NX8  (S_LEN * HID / 8)
#define NW8  (3 * HID * HID / 8)
#define NO8  (HID * HID / 8)
__global__ void k_cvt_all(const float* __restrict__ x, const float* __restrict__ wq,
                          const float* __restrict__ wo, _Float16* __restrict__ x16,
                          _Float16* __restrict__ wq16, _Float16* __restrict__ wo16) {
  int i = blockIdx.x * 256 + threadIdx.x;
  const float* src; _Float16* dst; int j;
  if (i < NX8)            { src = x;  dst = x16;  j = i; }
  else if (i < NX8 + NW8) { src = wq; dst = wq16; j = i - NX8; }
  else                    { src = wo; dst = wo16; j = i - NX8 - NW8; }
  float4 a = ((const float4*)src)[2 * j];
  float4 b = ((const float4*)src)[2 * j + 1];
  half8 h;
  h[0] = (_Float16)a.x; h[1] = (_Float16)a.y; h[2] = (_Float16)a.z; h[3] = (_Float16)a.w;
  h[4] = (_Float16)b.x; h[5] = (_Float16)b.y; h[6] = (_Float16)b.z; h[7] = (_Float16)b.w;
  ((half8*)dst)[j] = h;
}

// ---------- rl = 1/(l0+l1) ----------
__global__ void k_rl(const float* __restrict__ l0, const float* __restrict__ l1,
                     _Float16* __restrict__ rlb) {
  int i = blockIdx.x * 256 + threadIdx.x;
  rlb[i] = (_Float16)(1.0f / (l0[i] + l1[i]));
}

// ---------- fp16 MFMA NT GEMM, BK=64, swizzled LDS, staged-under-MFMA ----------
// MODE 0: f16 C; MODE 2: write pre-swizzled K/Vt images (KV GEMM)
template<int MODE>
__global__ __launch_bounds__(256)
void k_gemm2(const _Float16* __restrict__ A, const _Float16* __restrict__ B,
             void* __restrict__ Cv, int M, int N, int K,
             const int* __restrict__ arow,
             char* __restrict__ kimg, char* __restrict__ vtimg)
{
  __shared__ __align__(16) char Asl[16384];
  __shared__ __align__(16) char Bsl[16384];
  const int tid = threadIdx.x;
  const int w = tid >> 6, lane = tid & 63;
  const int l15 = lane & 15, l4 = lane >> 4;
  const int m0 = blockIdx.y * 128, n0 = blockIdx.x * 128;
  const int wr = w >> 1, wc = w & 1;

  const int srow  = lane >> 3;
  const int kso   = ((lane & 7) ^ srow) * 8;   // f16 elements
  const _Float16* Ap[4];
  const _Float16* Bp[4];
#pragma unroll
  for (int q = 0; q < 4; ++q) {
    int arel = m0 + 32 * w + 8 * q + srow;
    int ra = arow ? arow[arel] : arel;
    Ap[q] = A + (size_t)ra * K + kso;
    Bp[q] = B + (size_t)(n0 + 32 * w + 8 * q + srow) * K + kso;
  }

  f32x4 acc[4][4];
#pragma unroll
  for (int i = 0; i < 4; ++i)
#pragma unroll
    for (int j = 0; j < 4; ++j) acc[i][j] = (f32x4){0.f, 0.f, 0.f, 0.f};

#define STAGE_T(k0)                                                  \
  do {                                                               \
    _Pragma("unroll")                                                \
    for (int q = 0; q < 4; ++q) {                                    \
      gload16(Ap[q] + (k0), Asl + (4 * w + q) * 1024 + lane * 16);   \
      gload16(Bp[q] + (k0), Bsl + (4 * w + q) * 1024 + lane * 16);   \
    }                                                                \
  } while (0)

  STAGE_T(0);
  __syncthreads();

  const int nt = K >> 6;
  for (int t = 0; t < nt; ++t) {
    half8 af[4][2], bf[4][2];
#pragma unroll
    for (int mi = 0; mi < 4; ++mi) {
      int row = wr * 64 + mi * 16 + l15;
#pragma unroll
      for (int ks = 0; ks < 2; ++ks)
        af[mi][ks] = *(const half8*)(Asl + row * 128 + (((ks * 4 + l4) ^ (row & 7)) * 16));
    }
#pragma unroll
    for (int ni = 0; ni < 4; ++ni) {
      int row = wc * 64 + ni * 16 + l15;
#pragma unroll
      for (int ks = 0; ks < 2; ++ks)
        bf[ni][ks] = *(const half8*)(Bsl + row * 128 + (((ks * 4 + l4) ^ (row & 7)) * 16));
    }
    __syncthreads();
    if (t + 1 < nt) STAGE_T((t + 1) * 64);
    __builtin_amdgcn_s_setprio(1);
#pragma unroll
    for (int mi = 0; mi < 4; ++mi)
#pragma unroll
      for (int ni = 0; ni < 4; ++ni)
#pragma unroll
        for (int ks = 0; ks < 2; ++ks)
          acc[mi][ni] = __builtin_amdgcn_mfma_f32_16x16x32_f16(af[mi][ks], bf[ni][ks], acc[mi][ni], 0, 0, 0);
    __builtin_amdgcn_s_setprio(0);
    __syncthreads();
  }
#undef STAGE_T

  const int rbase = m0 + wr * 64 + l4 * 4;
  const int cbase = n0 + wc * 64 + l15;
#pragma unroll
  for (int mi = 0; mi < 4; ++mi)
#pragma unroll
    for (int ni = 0; ni < 4; ++ni)
#pragma unroll
      for (int e = 0; e < 4; ++e) {
        int row = rbase + mi * 16 + e;
        int col = cbase + ni * 16;
        if (MODE == 0) {
          ((_Float16*)Cv)[(size_t)row * N + col] = (_Float16)acc[mi][ni][e];
        } else {
          _Float16 val = (_Float16)acc[mi][ni][e];
          int t = row >> 6, j = row & 63;
          if (col < HID) {
            int h = col >> 7, d = col & 127;
            int off = (h * 32 + t) * 16384 + ((j * 256 + 2 * d) ^ ((j & 7) << 4));
            *(_Float16*)(kimg + off) = val;
          } else {
            int nn = col - HID;
            int h = nn >> 7, d = nn & 127;
            int off = (h * 32 + t) * 16384 + ((d * 128 + 2 * j) ^ ((d & 7) << 4));
            *(_Float16*)(vtimg + off) = val;
          }
        }
      }
}

// ---------- out GEMM: A = (a0+a1)*rl reg-staged combine, B gload_lds, f32 C ----------
__global__ __launch_bounds__(256)
void k_gemm_out(const _Float16* __restrict__ A0, const _Float16* __restrict__ A1,
                const _Float16* __restrict__ rlb, const _Float16* __restrict__ B,
                float* __restrict__ C, int M, int N, int K)
{
  __shared__ __align__(16) char Asl[16384];
  __shared__ __align__(16) char Bsl[16384];
  const int tid = threadIdx.x;
  const int w = tid >> 6, lane = tid & 63;
  const int l15 = lane & 15, l4 = lane >> 4;
  const int m0 = blockIdx.y * 128, n0 = blockIdx.x * 128;
  const int wr = w >> 1, wc = w & 1;

  const int srow  = lane >> 3;
  const int kso   = ((lane & 7) ^ srow) * 8;
  const _Float16* Ap0[4];
  const _Float16* Ap1[4];
  const _Float16* Bp[4];
  const _Float16* Rp[4];
#pragma unroll
  for (int q = 0; q < 4; ++q) {
    int row = m0 + 32 * w + 8 * q + srow;
    Ap0[q] = A0 + (size_t)row * K + kso;
    Ap1[q] = A1 + (size_t)row * K + kso;
    Rp[q]  = rlb + row * NH;
    Bp[q] = B + (size_t)(n0 + 32 * w + 8 * q + srow) * K + kso;
  }

  f32x4 acc[4][4];
#pragma unroll
  for (int i = 0; i < 4; ++i)
#pragma unroll
    for (int j = 0; j < 4; ++j) acc[i][j] = (f32x4){0.f, 0.f, 0.f, 0.f};

#define STAGE_O(k0)                                                   \
  do {                                                                \
    _Pragma("unroll")                                                 \
    for (int q = 0; q < 4; ++q) {                                     \
      half8 v0 = *(const half8*)(Ap0[q] + (k0));                      \
      half8 v1 = *(const half8*)(Ap1[q] + (k0));                      \
      _Float16 rl = Rp[q][((k0) + kso) >> 7];                         \
      half8 s = v0 + v1;                                              \
      _Pragma("unroll")                                               \
      for (int e = 0; e < 8; ++e) s[e] *= rl;                         \
      *(half8*)(Asl + (4 * w + q) * 1024 + lane * 16) = s;            \
      gload16(Bp[q] + (k0), Bsl + (4 * w + q) * 1024 + lane * 16);    \
    }                                                                 \
  } while (0)

  STAGE_O(0);
  __syncthreads();

  const int nt = K >> 6;
  for (int t = 0; t < nt; ++t) {
    half8 af[4][2], bf[4][2];
#pragma unroll
    for (int mi = 0; mi < 4; ++mi) {
      int row = wr * 64 + mi * 16 + l15;
#pragma unroll
      for (int ks = 0; ks < 2; ++ks)
        af[mi][ks] = *(const half8*)(Asl + row * 128 + (((ks * 4 + l4) ^ (row & 7)) * 16));
    }
#pragma unroll
    for (int ni = 0; ni < 4; ++ni) {
      int row = wc * 64 + ni * 16 + l15;
#pragma unroll
      for (int ks = 0; ks < 2; ++ks)
        bf[ni][ks] = *(const half8*)(Bsl + row * 128 + (((ks * 4 + l4) ^ (row & 7)) * 16));
    }
    __syncthreads();
    if (t + 1 < nt) STAGE_O((t + 1) * 64);
    __builtin_amdgcn_s_setprio(1);
#pragma unroll
    for (int mi = 0; mi < 4; ++mi)
#pragma unroll
      for (int ni = 0; ni < 4; ++ni)
#pragma unroll
        for (int ks = 0; ks < 2; ++ks)
          acc[mi][ni] = __builtin_amdgcn_mfma_f32_16x16x32_f16(af[mi][ks], bf[ni][ks], acc[mi][ni], 0, 0, 0);
    __builtin_amdgcn_s_setprio(0);
    __syncthreads();
  }
#undef STAGE_O

  const int rbase = m0 + wr * 64 + l4 * 4;
  const int cbase = n0 + wc * 64 + l15;
#pragma unroll
  for (int mi = 0; mi < 4; ++mi)
#pragma unroll
    for (int ni = 0; ni < 4; ++ni)
#pragma unroll
      for (int e = 0; e < 4; ++e)
        C[(size_t)(rbase + mi * 16 + e) * N + cbase + ni * 16] = acc[mi][ni][e];
}

// ---------- 32x32 MFMA flash attention: kv-split halves, 2 blocks/CU ----------
// 512 threads = 8 waves; wave owns 32 q rows (q = l&31). Block handles 16 of the
// 32 KV tiles; writes UNNORMALIZED O (f16) + partial l. grid = 512 (2 blocks/CU).
__global__ __launch_bounds__(512, 4)
void k_attn8(const _Float16* __restrict__ qmat, const char* __restrict__ kimg,
             const char* __restrict__ vtimg, const int* __restrict__ hmap,
             _Float16* __restrict__ a0, _Float16* __restrict__ a1,
             float* __restrict__ l0, float* __restrict__ l1)
{
  extern __shared__ __align__(16) char lds[];
  const int tid = threadIdx.x;
  const int w = tid >> 6, lane = tid & 63;
  const int l31 = lane & 31;
  const bool hi = (lane >> 5) != 0;
  const int hib = hi ? 1 : 0;
  const int work = (blockIdx.x & 7) * 64 + (blockIdx.x >> 3);  // XCD-chunked bijective (512)
  const int half = work & 1;
  const int pi   = work >> 1;
  const int h  = pi >> 4;
  const int q0 = (pi & 15) * QBLK;
  const int t0 = half * (NT / 2);
  const int tend = t0 + NT / 2;

  half8 qf[8];
  {
    const int qrow = q0 + w * 32 + l31;
    const _Float16* qb = qmat + (size_t)qrow * HID + h * HD + hib * 8;
    const _Float16 qs = (_Float16)QSCALE;
#pragma unroll
    for (int dk = 0; dk < 8; ++dk) {
      half8 v = *(const half8*)(qb + 16 * dk);
#pragma unroll
      for (int q = 0; q < 8; ++q) v[q] *= qs;
      qf[dk] = v;
    }
  }

  half8 ones;
#pragma unroll
  for (int q = 0; q < 8; ++q) ones[q] = (_Float16)1.0f;

  const int swz = (l31 & 7) << 4;
  int koff[4], voff[4];
#pragma unroll
  for (int i = 0; i < 4; ++i) {
    koff[i] = l31 * 256 + ((i * 32 + hib * 16) ^ swz);
    voff[i] = 16384 + l31 * 128 + ((i * 32 + hib * 16) ^ swz);
  }

  const char* kbase = kimg  + (size_t)h * NT * 16384;
  const char* vbase = vtimg + (size_t)h * NT * 16384;

  f32x16 acc[4];
  f32x16 accl;
#pragma unroll
  for (int dt = 0; dt < 4; ++dt)
#pragma unroll
    for (int r = 0; r < 16; ++r) acc[dt][r] = 0.f;
#pragma unroll
  for (int r = 0; r < 16; ++r) accl[r] = 0.f;

#define STAGE(buf, t)                                                          \
  do {                                                                         \
    const char* ks_ = kbase + (size_t)(t) * 16384;                             \
    const char* vs_ = vbase + (size_t)(t) * 16384;                             \
    char* d_ = lds + (buf) * 32768;                                            \
    gload16(ks_ + w * 1024 + lane * 16,          d_ + w * 1024);               \
    gload16(ks_ + (8 + w) * 1024 + lane * 16,    d_ + (8 + w) * 1024);         \
    gload16(vs_ + w * 1024 + lane * 16,          d_ + 16384 + w * 1024);       \
    gload16(vs_ + (8 + w) * 1024 + lane * 16,    d_ + 16384 + (8 + w) * 1024); \
  } while (0)

#define TILE(CUR, T)                                                           \
  do {                                                                         \
    if ((T) + 1 < tend) STAGE((CUR) ^ 1, (T) + 1);                             \
    f32x16 s[2];                                                               \
    __builtin_amdgcn_s_setprio(1);                                             \
    _Pragma("unroll")                                                          \
    for (int jt = 0; jt < 2; ++jt) {                                           \
      f32x16 ss;                                                               \
      _Pragma("unroll")                                                        \
      for (int r = 0; r < 16; ++r) ss[r] = 0.f;                                \
      _Pragma("unroll")                                                        \
      for (int dk = 0; dk < 8; ++dk) {                                         \
        half8 kf = *(const half8*)(lds + koff[dk & 3] +                        \
                    ((CUR) * 32768 + jt * 8192 + (dk >> 2) * 128));            \
        ss = __builtin_amdgcn_mfma_f32_32x32x16_f16(kf, qf[dk], ss, 0, 0, 0);  \
      }                                                                        \
      s[jt] = ss;                                                              \
    }                                                                          \
    __builtin_amdgcn_s_setprio(0);                                             \
    unsigned P_pk[2][4][2];                                                    \
    _Pragma("unroll")                                                          \
    for (int jt = 0; jt < 2; ++jt)                                             \
      _Pragma("unroll")                                                        \
      for (int rq = 0; rq < 4; ++rq)                                           \
        _Pragma("unroll")                                                      \
        for (int h2 = 0; h2 < 2; ++h2) {                                       \
          float p0 = exp2f(s[jt][4 * rq + 2 * h2]);                            \
          float p1 = exp2f(s[jt][4 * rq + 2 * h2 + 1]);                        \
          P_pk[jt][rq][h2] = pkrtz(p0, p1);                                    \
        }                                                                      \
    _Pragma("unroll")                                                          \
    for (int ks = 0; ks < 4; ++ks) {                                           \
      const int jt = ks >> 1, k1 = ks & 1;                                     \
      unsigned send0 = hi ? P_pk[jt][2 * k1][0]     : P_pk[jt][2 * k1 + 1][0]; \
      unsigned send1 = hi ? P_pk[jt][2 * k1][1]     : P_pk[jt][2 * k1 + 1][1]; \
      unsigned recv0 = (unsigned)__shfl_xor((int)send0, 32);                   \
      unsigned recv1 = (unsigned)__shfl_xor((int)send1, 32);                   \
      unsigned self0 = hi ? P_pk[jt][2 * k1 + 1][0] : P_pk[jt][2 * k1][0];     \
      unsigned self1 = hi ? P_pk[jt][2 * k1 + 1][1] : P_pk[jt][2 * k1][1];     \
      union { unsigned u[4]; half8 hv; } pf;                                   \
      pf.u[0] = hi ? recv0 : self0;                                            \
      pf.u[1] = hi ? recv1 : self1;                                            \
      pf.u[2] = hi ? self0 : recv0;                                            \
      pf.u[3] = hi ? self1 : recv1;                                            \
      __builtin_amdgcn_s_setprio(1);                                           \
      _Pragma("unroll")                                                        \
      for (int dt = 0; dt < 4; ++dt) {                                         \
        half8 vf = *(const half8*)(lds + voff[ks] +                            \
                    ((CUR) * 32768 + dt * 4096));                              \
        acc[dt] = __builtin_amdgcn_mfma_f32_32x32x16_f16(vf, pf.hv, acc[dt], 0, 0, 0); \
      }                                                                        \
      accl = __builtin_amdgcn_mfma_f32_32x32x16_f16(ones, pf.hv, accl, 0, 0, 0); \
      __builtin_amdgcn_s_setprio(0);                                           \
    }                                                                          \
    asm volatile("s_waitcnt vmcnt(0)");                                        \
    __syncthreads();                                                           \
  } while (0)

  STAGE(0, t0);
  asm volatile("s_waitcnt vmcnt(0)");
  __syncthreads();

  for (int t = t0; t < tend; t += 2) {
    TILE(0, t);
    TILE(1, t + 1);
  }
#undef TILE
#undef STAGE

  // epilogue: UNNORMALIZED partial O (f16) + partial l, scattered by hmap
  const int qrow = q0 + w * 32 + l31;
  const int srow = hmap[qrow];
  _Float16* ob = (half ? a1 : a0) + (size_t)srow * HID + h * HD;
#pragma unroll
  for (int dt = 0; dt < 4; ++dt)
#pragma unroll
    for (int rq = 0; rq < 4; ++rq) {
      const int d0 = dt * 32 + 8 * rq + 4 * hib;
      half4 o;
      o[0] = (_Float16)acc[dt][4 * rq + 0];
      o[1] = (_Float16)acc[dt][4 * rq + 1];
      o[2] = (_Float16)acc[dt][4 * rq + 2];
      o[3] = (_Float16)acc[dt][4 * rq + 3];
      *(half4*)(ob + d0) = o;
    }
  if (!hi) (half ? l1 : l0)[srow * NH + h] = accl[0];
}

extern "C" void kernel_launch(void* const* d_in, const int* in_sizes, int n_in,
                              void* d_out, int out_size, void* d_ws, size_t ws_size,
                              hipStream_t stream)
{
  const float* x     = (const float*)d_in[0];
  const float* w_qkv = (const float*)d_in[1];
  const float* w_out = (const float*)d_in[2];
  const int*   hmap  = (const int*)d_in[3];
  float* out = (float*)d_out;

  char* ws = (char*)d_ws;
  int* gidx = (int*)ws;                                          ws += 8192;
  _Float16* x16    = (_Float16*)ws;  // aliased with a0 (x16 dead after QKV GEMMs)
  _Float16* a0     = (_Float16*)ws;                              ws += (size_t)S_LEN * HID * 2;
  _Float16* a1     = (_Float16*)ws;                              ws += (size_t)S_LEN * HID * 2;
  _Float16* wqkv16 = (_Float16*)ws;                              ws += (size_t)3 * HID * HID * 2;
  _Float16* wout16 = (_Float16*)ws;                              ws += (size_t)HID * HID * 2;
  _Float16* q16    = (_Float16*)ws;                              ws += (size_t)S_LEN * HID * 2;
  char* kimg  = ws;                                              ws += (size_t)NH * NT * 16384;
  char* vtimg = ws;                                              ws += (size_t)NH * NT * 16384;
  float* l0   = (float*)ws;                                      ws += S_LEN * NH * 4;
  float* l1   = (float*)ws;                                      ws += S_LEN * NH * 4;
  _Float16* rlb = (_Float16*)ws;

  k_build_idx<<<8, 256, 0, stream>>>(hmap, gidx);
  k_cvt_all<<<(NX8 + NW8 + NO8 + 255) / 256, 256, 0, stream>>>(x, w_qkv, w_out,
                                                               x16, wqkv16, wout16);

  // Q = x @ wq^T  (4096 x 2048)
  dim3 gq(HID / 128, S_LEN / 128);
  k_gemm2<0><<<gq, 256, 0, stream>>>(x16, wqkv16, q16, S_LEN, HID, HID, nullptr, nullptr, nullptr);
  // KV = x[gidx] @ wkv^T  (2048 x 4096) -> written directly as swizzled K/Vt images
  dim3 gkv(2 * HID / 128, NKV / 128);
  k_gemm2<2><<<gkv, 256, 0, stream>>>(x16, wqkv16 + (size_t)HID * HID, nullptr,
                                      NKV, 2 * HID, HID, gidx, kimg, vtimg);

  // attention halves (2 blocks/CU)
  k_attn8<<<2 * NH * (S_LEN / QBLK), 512, 65536, stream>>>(q16, kimg, vtimg, hmap,
                                                           a0, a1, l0, l1);
  k_rl<<<S_LEN * NH / 256, 256, 0, stream>>>(l0, l1, rlb);

  // out = ((a0+a1)*rl) @ w_out^T  (4096 x 2048, fp32), combine fused into A-staging
  dim3 go(HID / 128, S_LEN / 128);
  k_gemm_out<<<go, 256, 0, stream>>>(a0, a1, rlb, wout16, out, S_LEN, HID, HID);
}

// Round 13
// 231.011 us; speedup vs baseline: 2.2276x; 2.2276x over previous
//
#include <hip/hip_runtime.h>
#include <math.h>

#define S_LEN 4096
#define HID   2048
#define NH    16
#define HD    128
#define NKV   2048
#define KT    64
#define QBLK  256
#define NT    (NKV / KT)
// (1/sqrt(128)) * log2(e) -- folded into Q so QK^T lands in exp2 domain
#define QSCALE 0.12754103668587426f

typedef __attribute__((ext_vector_type(8))) _Float16 half8;
typedef __attribute__((ext_vector_type(4))) _Float16 half4;
typedef __attribute__((ext_vector_type(2))) __fp16 fp16x2;
typedef __attribute__((ext_vector_type(4))) float f32x4;
typedef __attribute__((ext_vector_type(16))) float f32x16;

#define GLB_AS __attribute__((address_space(1)))
#define LDS_AS __attribute__((address_space(3)))

__device__ __forceinline__ void gload16(const void* g, void* l) {
  __builtin_amdgcn_global_load_lds((GLB_AS const void*)g, (LDS_AS void*)l, 16, 0, 0);
}

__device__ __forceinline__ unsigned pkrtz(float a, float b) {
  union { fp16x2 h; unsigned u; } cv;
  cv.h = __builtin_amdgcn_cvt_pkrtz(a, b);
  return cv.u;
}

// ---------- index build ----------
__global__ void k_build_idx(const int* __restrict__ hmap, int* __restrict__ gidx) {
  int i = blockIdx.x * 256 + threadIdx.x;
  if (i < NKV) gidx[i] = hmap[2 * i];
}

// ---------- fused fp32 -> fp16 conversion for x, w_qkv, w_out ----------
#define NX8  (S_LEN * HID / 8)
#define NW8  (3 * HID * HID / 8)
#define NO8  (HID * HID / 8)
__global__ void k_cvt_all(const float* __restrict__ x, const float* __restrict__ wq,
                          const float* __restrict__ wo, _Float16* __restrict__ x16,
                          _Float16* __restrict__ wq16, _Float16* __restrict__ wo16) {
  int i = blockIdx.x * 256 + threadIdx.x;
  const float* src; _Float16* dst; int j;
  if (i < NX8)            { src = x;  dst = x16;  j = i; }
  else if (i < NX8 + NW8) { src = wq; dst = wq16; j = i - NX8; }
  else                    { src = wo; dst = wo16; j = i - NX8 - NW8; }
  float4 a = ((const float4*)src)[2 * j];
  float4 b = ((const float4*)src)[2 * j + 1];
  half8 h;
  h[0] = (_Float16)a.x; h[1] = (_Float16)a.y; h[2] = (_Float16)a.z; h[3] = (_Float16)a.w;
  h[4] = (_Float16)b.x; h[5] = (_Float16)b.y; h[6] = (_Float16)b.z; h[7] = (_Float16)b.w;
  ((half8*)dst)[j] = h;
}

// ---------- fp16 MFMA NT GEMM, BK=64, swizzled LDS, staged-under-MFMA ----------
// MODE 0: f16 C; MODE 1: f32 C; MODE 2: write pre-swizzled K/Vt images (KV GEMM)
template<int MODE>
__global__ __launch_bounds__(256)
void k_gemm2(const _Float16* __restrict__ A, const _Float16* __restrict__ B,
             void* __restrict__ Cv, int M, int N, int K,
             const int* __restrict__ arow,
             char* __restrict__ kimg, char* __restrict__ vtimg)
{
  __shared__ __align__(16) char Asl[16384];
  __shared__ __align__(16) char Bsl[16384];
  const int tid = threadIdx.x;
  const int w = tid >> 6, lane = tid & 63;
  const int l15 = lane & 15, l4 = lane >> 4;
  const int m0 = blockIdx.y * 128, n0 = blockIdx.x * 128;
  const int wr = w >> 1, wc = w & 1;

  const int srow  = lane >> 3;
  const int kso   = ((lane & 7) ^ srow) * 8;   // f16 elements
  const _Float16* Ap[4];
  const _Float16* Bp[4];
#pragma unroll
  for (int q = 0; q < 4; ++q) {
    int arel = m0 + 32 * w + 8 * q + srow;
    int ra = arow ? arow[arel] : arel;
    Ap[q] = A + (size_t)ra * K + kso;
    Bp[q] = B + (size_t)(n0 + 32 * w + 8 * q + srow) * K + kso;
  }

  f32x4 acc[4][4];
#pragma unroll
  for (int i = 0; i < 4; ++i)
#pragma unroll
    for (int j = 0; j < 4; ++j) acc[i][j] = (f32x4){0.f, 0.f, 0.f, 0.f};

#define STAGE_T(k0)                                                  \
  do {                                                               \
    _Pragma("unroll")                                                \
    for (int q = 0; q < 4; ++q) {                                    \
      gload16(Ap[q] + (k0), Asl + (4 * w + q) * 1024 + lane * 16);   \
      gload16(Bp[q] + (k0), Bsl + (4 * w + q) * 1024 + lane * 16);   \
    }                                                                \
  } while (0)

  STAGE_T(0);
  __syncthreads();

  const int nt = K >> 6;
  for (int t = 0; t < nt; ++t) {
    half8 af[4][2], bf[4][2];
#pragma unroll
    for (int mi = 0; mi < 4; ++mi) {
      int row = wr * 64 + mi * 16 + l15;
#pragma unroll
      for (int ks = 0; ks < 2; ++ks)
        af[mi][ks] = *(const half8*)(Asl + row * 128 + (((ks * 4 + l4) ^ (row & 7)) * 16));
    }
#pragma unroll
    for (int ni = 0; ni < 4; ++ni) {
      int row = wc * 64 + ni * 16 + l15;
#pragma unroll
      for (int ks = 0; ks < 2; ++ks)
        bf[ni][ks] = *(const half8*)(Bsl + row * 128 + (((ks * 4 + l4) ^ (row & 7)) * 16));
    }
    __syncthreads();
    if (t + 1 < nt) STAGE_T((t + 1) * 64);
    __builtin_amdgcn_s_setprio(1);
#pragma unroll
    for (int mi = 0; mi < 4; ++mi)
#pragma unroll
      for (int ni = 0; ni < 4; ++ni)
#pragma unroll
        for (int ks = 0; ks < 2; ++ks)
          acc[mi][ni] = __builtin_amdgcn_mfma_f32_16x16x32_f16(af[mi][ks], bf[ni][ks], acc[mi][ni], 0, 0, 0);
    __builtin_amdgcn_s_setprio(0);
    __syncthreads();
  }
#undef STAGE_T

  const int rbase = m0 + wr * 64 + l4 * 4;
  const int cbase = n0 + wc * 64 + l15;
#pragma unroll
  for (int mi = 0; mi < 4; ++mi)
#pragma unroll
    for (int ni = 0; ni < 4; ++ni)
#pragma unroll
      for (int e = 0; e < 4; ++e) {
        int row = rbase + mi * 16 + e;
        int col = cbase + ni * 16;
        if (MODE == 1) {
          ((float*)Cv)[(size_t)row * N + col] = acc[mi][ni][e];
        } else if (MODE == 0) {
          ((_Float16*)Cv)[(size_t)row * N + col] = (_Float16)acc[mi][ni][e];
        } else {
          _Float16 val = (_Float16)acc[mi][ni][e];
          int t = row >> 6, j = row & 63;
          if (col < HID) {
            int h = col >> 7, d = col & 127;
            int off = (h * 32 + t) * 16384 + ((j * 256 + 2 * d) ^ ((j & 7) << 4));
            *(_Float16*)(kimg + off) = val;
          } else {
            int nn = col - HID;
            int h = nn >> 7, d = nn & 127;
            int off = (h * 32 + t) * 16384 + ((d * 128 + 2 * j) ^ ((d & 7) << 4));
            *(_Float16*)(vtimg + off) = val;
          }
        }
      }
}

// ---------- 32x32 MFMA flash attention: no-max softmax, hoisted LDS offsets ----------
// 512 threads = 8 waves; wave owns 32 q rows (q = l&31); KV tiles of 64.
// grid = 256 blocks (1/CU). LDS 2 x (K 16KB + Vt 16KB) = 64KB.
// l accumulated as in-lane f32 psum (halves hold disjoint j-sets) + 1 end shfl.
__global__ __launch_bounds__(512, 2)
void k_attn7(const _Float16* __restrict__ qmat, const char* __restrict__ kimg,
             const char* __restrict__ vtimg, const int* __restrict__ hmap,
             _Float16* __restrict__ att)
{
  extern __shared__ __align__(16) char lds[];
  const int tid = threadIdx.x;
  const int w = tid >> 6, lane = tid & 63;
  const int l31 = lane & 31;
  const bool hi = (lane >> 5) != 0;
  const int hib = hi ? 1 : 0;
  const int work = (blockIdx.x & 7) * 32 + (blockIdx.x >> 3);  // XCD-chunked, bijective
  const int h  = work >> 4;
  const int q0 = (work & 15) * QBLK;

  half8 qf[8];
  {
    const int qrow = q0 + w * 32 + l31;
    const _Float16* qb = qmat + (size_t)qrow * HID + h * HD + hib * 8;
    const _Float16 qs = (_Float16)QSCALE;
#pragma unroll
    for (int dk = 0; dk < 8; ++dk) {
      half8 v = *(const half8*)(qb + 16 * dk);
#pragma unroll
      for (int q = 0; q < 8; ++q) v[q] *= qs;
      qf[dk] = v;
    }
  }

  const int swz = (l31 & 7) << 4;
  int koff[4], voff[4];
#pragma unroll
  for (int i = 0; i < 4; ++i) {
    koff[i] = l31 * 256 + ((i * 32 + hib * 16) ^ swz);
    voff[i] = 16384 + l31 * 128 + ((i * 32 + hib * 16) ^ swz);
  }

  const char* kbase = kimg  + (size_t)h * NT * 16384;
  const char* vbase = vtimg + (size_t)h * NT * 16384;

  f32x16 acc[4];
#pragma unroll
  for (int dt = 0; dt < 4; ++dt)
#pragma unroll
    for (int r = 0; r < 16; ++r) acc[dt][r] = 0.f;
  float lsum = 0.f;

#define STAGE(buf, t)                                                          \
  do {                                                                         \
    const char* ks_ = kbase + (size_t)(t) * 16384;                             \
    const char* vs_ = vbase + (size_t)(t) * 16384;                             \
    char* d_ = lds + (buf) * 32768;                                            \
    gload16(ks_ + w * 1024 + lane * 16,          d_ + w * 1024);               \
    gload16(ks_ + (8 + w) * 1024 + lane * 16,    d_ + (8 + w) * 1024);         \
    gload16(vs_ + w * 1024 + lane * 16,          d_ + 16384 + w * 1024);       \
    gload16(vs_ + (8 + w) * 1024 + lane * 16,    d_ + 16384 + (8 + w) * 1024); \
  } while (0)

#define TILE(CUR, T)                                                           \
  do {                                                                         \
    if ((T) + 1 < NT) STAGE((CUR) ^ 1, (T) + 1);                               \
    f32x16 s[2];                                                               \
    __builtin_amdgcn_s_setprio(1);                                             \
    _Pragma("unroll")                                                          \
    for (int jt = 0; jt < 2; ++jt) {                                           \
      f32x16 ss;                                                               \
      _Pragma("unroll")                                                        \
      for (int r = 0; r < 16; ++r) ss[r] = 0.f;                                \
      _Pragma("unroll")                                                        \
      for (int dk = 0; dk < 8; ++dk) {                                         \
        half8 kf = *(const half8*)(lds + koff[dk & 3] +                        \
                    ((CUR) * 32768 + jt * 8192 + (dk >> 2) * 128));            \
        ss = __builtin_amdgcn_mfma_f32_32x32x16_f16(kf, qf[dk], ss, 0, 0, 0);  \
      }                                                                        \
      s[jt] = ss;                                                              \
    }                                                                          \
    __builtin_amdgcn_s_setprio(0);                                             \
    unsigned P_pk[2][4][2];                                                    \
    _Pragma("unroll")                                                          \
    for (int jt = 0; jt < 2; ++jt)                                             \
      _Pragma("unroll")                                                        \
      for (int rq = 0; rq < 4; ++rq)                                           \
        _Pragma("unroll")                                                      \
        for (int h2 = 0; h2 < 2; ++h2) {                                       \
          float p0 = exp2f(s[jt][4 * rq + 2 * h2]);                            \
          float p1 = exp2f(s[jt][4 * rq + 2 * h2 + 1]);                        \
          lsum += p0 + p1;                                                     \
          P_pk[jt][rq][h2] = pkrtz(p0, p1);                                    \
        }                                                                      \
    _Pragma("unroll")                                                          \
    for (int ks = 0; ks < 4; ++ks) {                                           \
      const int jt = ks >> 1, k1 = ks & 1;                                     \
      unsigned send0 = hi ? P_pk[jt][2 * k1][0]     : P_pk[jt][2 * k1 + 1][0]; \
      unsigned send1 = hi ? P_pk[jt][2 * k1][1]     : P_pk[jt][2 * k1 + 1][1]; \
      unsigned recv0 = (unsigned)__shfl_xor((int)send0, 32);                   \
      unsigned recv1 = (unsigned)__shfl_xor((int)send1, 32);                   \
      unsigned self0 = hi ? P_pk[jt][2 * k1 + 1][0] : P_pk[jt][2 * k1][0];     \
      unsigned self1 = hi ? P_pk[jt][2 * k1 + 1][1] : P_pk[jt][2 * k1][1];     \
      union { unsigned u[4]; half8 hv; } pf;                                   \
      pf.u[0] = hi ? recv0 : self0;                                            \
      pf.u[1] = hi ? recv1 : self1;                                            \
      pf.u[2] = hi ? self0 : recv0;                                            \
      pf.u[3] = hi ? self1 : recv1;                                            \
      __builtin_amdgcn_s_setprio(1);                                           \
      _Pragma("unroll")                                                        \
      for (int dt = 0; dt < 4; ++dt) {                                         \
        half8 vf = *(const half8*)(lds + voff[ks] +                            \
                    ((CUR) * 32768 + dt * 4096));                              \
        acc[dt] = __builtin_amdgcn_mfma_f32_32x32x16_f16(vf, pf.hv, acc[dt], 0, 0, 0); \
      }                                                                        \
      __builtin_amdgcn_s_setprio(0);                                           \
    }                                                                          \
    asm volatile("s_waitcnt vmcnt(0)");                                        \
    __syncthreads();                                                           \
  } while (0)

  STAGE(0, 0);
  asm volatile("s_waitcnt vmcnt(0)");
  __syncthreads();

  for (int t = 0; t < NT; t += 2) {
    TILE(0, t);
    TILE(1, t + 1);
  }
#undef TILE
#undef STAGE

  // epilogue: combine l across halves (disjoint j-sets), normalize, scatter by hmap
  float lt = lsum + __shfl_xor(lsum, 32);
  const float rl = 1.0f / lt;
  const int qrow = q0 + w * 32 + l31;
  const int srow = hmap[qrow];
  _Float16* ob = att + (size_t)srow * HID + h * HD;
#pragma unroll
  for (int dt = 0; dt < 4; ++dt)
#pragma unroll
    for (int rq = 0; rq < 4; ++rq) {
      const int d0 = dt * 32 + 8 * rq + 4 * hib;
      half4 o;
      o[0] = (_Float16)(acc[dt][4 * rq + 0] * rl);
      o[1] = (_Float16)(acc[dt][4 * rq + 1] * rl);
      o[2] = (_Float16)(acc[dt][4 * rq + 2] * rl);
      o[3] = (_Float16)(acc[dt][4 * rq + 3] * rl);
      *(half4*)(ob + d0) = o;
    }
}

extern "C" void kernel_launch(void* const* d_in, const int* in_sizes, int n_in,
                              void* d_out, int out_size, void* d_ws, size_t ws_size,
                              hipStream_t stream)
{
  const float* x     = (const float*)d_in[0];
  const float* w_qkv = (const float*)d_in[1];
  const float* w_out = (const float*)d_in[2];
  const int*   hmap  = (const int*)d_in[3];
  float* out = (float*)d_out;

  char* ws = (char*)d_ws;
  int* gidx = (int*)ws;                                          ws += 8192;
  _Float16* x16    = (_Float16*)ws;  // aliased with att16 (x16 dead after QKV GEMMs)
  _Float16* att16  = (_Float16*)ws;                              ws += (size_t)S_LEN * HID * 2;
  _Float16* wqkv16 = (_Float16*)ws;                              ws += (size_t)3 * HID * HID * 2;
  _Float16* wout16 = (_Float16*)ws;                              ws += (size_t)HID * HID * 2;
  _Float16* q16    = (_Float16*)ws;                              ws += (size_t)S_LEN * HID * 2;
  char* kimg  = ws;                                              ws += (size_t)NH * NT * 16384;
  char* vtimg = ws;

  k_build_idx<<<8, 256, 0, stream>>>(hmap, gidx);
  k_cvt_all<<<(NX8 + NW8 + NO8 + 255) / 256, 256, 0, stream>>>(x, w_qkv, w_out,
                                                               x16, wqkv16, wout16);

  // Q = x @ wq^T  (4096 x 2048)
  dim3 gq(HID / 128, S_LEN / 128);
  k_gemm2<0><<<gq, 256, 0, stream>>>(x16, wqkv16, q16, S_LEN, HID, HID, nullptr, nullptr, nullptr);
  // KV = x[gidx] @ wkv^T  (2048 x 4096) -> written directly as swizzled K/Vt images
  dim3 gkv(2 * HID / 128, NKV / 128);
  k_gemm2<2><<<gkv, 256, 0, stream>>>(x16, wqkv16 + (size_t)HID * HID, nullptr,
                                      NKV, 2 * HID, HID, gidx, kimg, vtimg);

  k_attn7<<<NH * (S_LEN / QBLK), 512, 65536, stream>>>(q16, kimg, vtimg, hmap, att16);

  // out = att @ w_out^T  (4096 x 2048, fp32)
  dim3 go(HID / 128, S_LEN / 128);
  k_gemm2<1><<<go, 256, 0, stream>>>(att16, wout16, out, S_LEN, HID, HID, nullptr, nullptr, nullptr);
}

// Round 14
// 217.922 us; speedup vs baseline: 2.3614x; 1.0601x over previous
//
#include <hip/hip_runtime.h>
#include <math.h>

#define S_LEN 4096
#define HID   2048
#define NH    16
#define HD    128
#define NKV   2048
#define KT    64
#define QBLK  256
#define NT    (NKV / KT)
// (1/sqrt(128)) * log2(e) -- folded into Q so QK^T lands in exp2 domain
#define QSCALE 0.12754103668587426f

typedef __attribute__((ext_vector_type(8))) _Float16 half8;
typedef __attribute__((ext_vector_type(4))) _Float16 half4;
typedef __attribute__((ext_vector_type(2))) __fp16 fp16x2;
typedef __attribute__((ext_vector_type(4))) float f32x4;
typedef __attribute__((ext_vector_type(16))) float f32x16;

#define GLB_AS __attribute__((address_space(1)))
#define LDS_AS __attribute__((address_space(3)))

#if __has_builtin(__builtin_amdgcn_exp2f)
#define EXP2(x) __builtin_amdgcn_exp2f(x)
#else
#define EXP2(x) exp2f(x)
#endif

__device__ __forceinline__ void gload16(const void* g, void* l) {
  __builtin_amdgcn_global_load_lds((GLB_AS const void*)g, (LDS_AS void*)l, 16, 0, 0);
}

__device__ __forceinline__ unsigned pkrtz(float a, float b) {
  union { fp16x2 h; unsigned u; } cv;
  cv.h = __builtin_amdgcn_cvt_pkrtz(a, b);
  return cv.u;
}

// ---------- index build ----------
__global__ void k_build_idx(const int* __restrict__ hmap, int* __restrict__ gidx) {
  int i = blockIdx.x * 256 + threadIdx.x;
  if (i < NKV) gidx[i] = hmap[2 * i];
}

// ---------- fused fp32 -> fp16 conversion for x, w_qkv, w_out ----------
#define NX8  (S_LEN * HID / 8)
#define NW8  (3 * HID * HID / 8)
#define NO8  (HID * HID / 8)
__global__ void k_cvt_all(const float* __restrict__ x, const float* __restrict__ wq,
                          const float* __restrict__ wo, _Float16* __restrict__ x16,
                          _Float16* __restrict__ wq16, _Float16* __restrict__ wo16) {
  int i = blockIdx.x * 256 + threadIdx.x;
  const float* src; _Float16* dst; int j;
  if (i < NX8)            { src = x;  dst = x16;  j = i; }
  else if (i < NX8 + NW8) { src = wq; dst = wq16; j = i - NX8; }
  else                    { src = wo; dst = wo16; j = i - NX8 - NW8; }
  float4 a = ((const float4*)src)[2 * j];
  float4 b = ((const float4*)src)[2 * j + 1];
  half8 h;
  h[0] = (_Float16)a.x; h[1] = (_Float16)a.y; h[2] = (_Float16)a.z; h[3] = (_Float16)a.w;
  h[4] = (_Float16)b.x; h[5] = (_Float16)b.y; h[6] = (_Float16)b.z; h[7] = (_Float16)b.w;
  ((half8*)dst)[j] = h;
}

// ---------- fp16 MFMA NT GEMM, BK=64, swizzled LDS, staged-under-MFMA ----------
// MODE 0: f16 C; MODE 1: f32 C; MODE 2: write pre-swizzled K/Vt images (KV GEMM)
template<int MODE>
__global__ __launch_bounds__(256)
void k_gemm2(const _Float16* __restrict__ A, const _Float16* __restrict__ B,
             void* __restrict__ Cv, int M, int N, int K,
             const int* __restrict__ arow,
             char* __restrict__ kimg, char* __restrict__ vtimg)
{
  __shared__ __align__(16) char Asl[16384];
  __shared__ __align__(16) char Bsl[16384];
  const int tid = threadIdx.x;
  const int w = tid >> 6, lane = tid & 63;
  const int l15 = lane & 15, l4 = lane >> 4;
  const int m0 = blockIdx.y * 128, n0 = blockIdx.x * 128;
  const int wr = w >> 1, wc = w & 1;

  const int srow  = lane >> 3;
  const int kso   = ((lane & 7) ^ srow) * 8;   // f16 elements
  const _Float16* Ap[4];
  const _Float16* Bp[4];
#pragma unroll
  for (int q = 0; q < 4; ++q) {
    int arel = m0 + 32 * w + 8 * q + srow;
    int ra = arow ? arow[arel] : arel;
    Ap[q] = A + (size_t)ra * K + kso;
    Bp[q] = B + (size_t)(n0 + 32 * w + 8 * q + srow) * K + kso;
  }

  f32x4 acc[4][4];
#pragma unroll
  for (int i = 0; i < 4; ++i)
#pragma unroll
    for (int j = 0; j < 4; ++j) acc[i][j] = (f32x4){0.f, 0.f, 0.f, 0.f};

#define STAGE_T(k0)                                                  \
  do {                                                               \
    _Pragma("unroll")                                                \
    for (int q = 0; q < 4; ++q) {                                    \
      gload16(Ap[q] + (k0), Asl + (4 * w + q) * 1024 + lane * 16);   \
      gload16(Bp[q] + (k0), Bsl + (4 * w + q) * 1024 + lane * 16);   \
    }                                                                \
  } while (0)

  STAGE_T(0);
  __syncthreads();

  const int nt = K >> 6;
  for (int t = 0; t < nt; ++t) {
    half8 af[4][2], bf[4][2];
#pragma unroll
    for (int mi = 0; mi < 4; ++mi) {
      int row = wr * 64 + mi * 16 + l15;
#pragma unroll
      for (int ks = 0; ks < 2; ++ks)
        af[mi][ks] = *(const half8*)(Asl + row * 128 + (((ks * 4 + l4) ^ (row & 7)) * 16));
    }
#pragma unroll
    for (int ni = 0; ni < 4; ++ni) {
      int row = wc * 64 + ni * 16 + l15;
#pragma unroll
      for (int ks = 0; ks < 2; ++ks)
        bf[ni][ks] = *(const half8*)(Bsl + row * 128 + (((ks * 4 + l4) ^ (row & 7)) * 16));
    }
    __syncthreads();
    if (t + 1 < nt) STAGE_T((t + 1) * 64);
    __builtin_amdgcn_s_setprio(1);
#pragma unroll
    for (int mi = 0; mi < 4; ++mi)
#pragma unroll
      for (int ni = 0; ni < 4; ++ni)
#pragma unroll
        for (int ks = 0; ks < 2; ++ks)
          acc[mi][ni] = __builtin_amdgcn_mfma_f32_16x16x32_f16(af[mi][ks], bf[ni][ks], acc[mi][ni], 0, 0, 0);
    __builtin_amdgcn_s_setprio(0);
    __syncthreads();
  }
#undef STAGE_T

  const int rbase = m0 + wr * 64 + l4 * 4;
  const int cbase = n0 + wc * 64 + l15;
#pragma unroll
  for (int mi = 0; mi < 4; ++mi)
#pragma unroll
    for (int ni = 0; ni < 4; ++ni)
#pragma unroll
      for (int e = 0; e < 4; ++e) {
        int row = rbase + mi * 16 + e;
        int col = cbase + ni * 16;
        if (MODE == 1) {
          ((float*)Cv)[(size_t)row * N + col] = acc[mi][ni][e];
        } else if (MODE == 0) {
          ((_Float16*)Cv)[(size_t)row * N + col] = (_Float16)acc[mi][ni][e];
        } else {
          _Float16 val = (_Float16)acc[mi][ni][e];
          int t = row >> 6, j = row & 63;
          if (col < HID) {
            int h = col >> 7, d = col & 127;
            int off = (h * 32 + t) * 16384 + ((j * 256 + 2 * d) ^ ((j & 7) << 4));
            *(_Float16*)(kimg + off) = val;
          } else {
            int nn = col - HID;
            int h = nn >> 7, d = nn & 127;
            int off = (h * 32 + t) * 16384 + ((d * 128 + 2 * j) ^ ((d & 7) << 4));
            *(_Float16*)(vtimg + off) = val;
          }
        }
      }
}

// ---------- 32x32 MFMA flash attention: half-tile software pipeline ----------
// 512 threads = 8 waves; wave owns 32 q rows (q = l&31); KV tiles of 64 split
// into two 32-j halves A/B. Order: QK_A, QK_B (MFMA clusters back-to-back),
// SM_A (hides under QK_B's chain), PV_A (MFMA) with SM_B's VALU in its shadow,
// PV_B. grid = 256 blocks (1/CU). LDS 2 x 32KB = 64KB.
__global__ __launch_bounds__(512, 2)
void k_attn9(const _Float16* __restrict__ qmat, const char* __restrict__ kimg,
             const char* __restrict__ vtimg, const int* __restrict__ hmap,
             _Float16* __restrict__ att)
{
  extern __shared__ __align__(16) char lds[];
  const int tid = threadIdx.x;
  const int w = tid >> 6, lane = tid & 63;
  const int l31 = lane & 31;
  const bool hi = (lane >> 5) != 0;
  const int hib = hi ? 1 : 0;
  const int work = (blockIdx.x & 7) * 32 + (blockIdx.x >> 3);  // XCD-chunked, bijective
  const int h  = work >> 4;
  const int q0 = (work & 15) * QBLK;

  half8 qf[8];
  {
    const int qrow = q0 + w * 32 + l31;
    const _Float16* qb = qmat + (size_t)qrow * HID + h * HD + hib * 8;
    const _Float16 qs = (_Float16)QSCALE;
#pragma unroll
    for (int dk = 0; dk < 8; ++dk) {
      half8 v = *(const half8*)(qb + 16 * dk);
#pragma unroll
      for (int q = 0; q < 8; ++q) v[q] *= qs;
      qf[dk] = v;
    }
  }

  const int swz = (l31 & 7) << 4;
  int koff[4], voff[4];
#pragma unroll
  for (int i = 0; i < 4; ++i) {
    koff[i] = l31 * 256 + ((i * 32 + hib * 16) ^ swz);
    voff[i] = 16384 + l31 * 128 + ((i * 32 + hib * 16) ^ swz);
  }

  const char* kbase = kimg  + (size_t)h * NT * 16384;
  const char* vbase = vtimg + (size_t)h * NT * 16384;

  f32x16 acc[4];
#pragma unroll
  for (int dt = 0; dt < 4; ++dt)
#pragma unroll
    for (int r = 0; r < 16; ++r) acc[dt][r] = 0.f;
  float lsum = 0.f;

#define STAGE(buf, t)                                                          \
  do {                                                                         \
    const char* ks_ = kbase + (size_t)(t) * 16384;                             \
    const char* vs_ = vbase + (size_t)(t) * 16384;                             \
    char* d_ = lds + (buf) * 32768;                                            \
    gload16(ks_ + w * 1024 + lane * 16,          d_ + w * 1024);               \
    gload16(ks_ + (8 + w) * 1024 + lane * 16,    d_ + (8 + w) * 1024);         \
    gload16(vs_ + w * 1024 + lane * 16,          d_ + 16384 + w * 1024);       \
    gload16(vs_ + (8 + w) * 1024 + lane * 16,    d_ + 16384 + (8 + w) * 1024); \
  } while (0)

// softmax of one 32-j half: s (f32x16) -> packed P (PPK[4][2]) + lsum
#define SM_HALF(S, PPK)                                                        \
  do {                                                                         \
    float p_[16];                                                              \
    _Pragma("unroll")                                                          \
    for (int r = 0; r < 16; ++r) { p_[r] = EXP2((S)[r]); lsum += p_[r]; }      \
    _Pragma("unroll")                                                          \
    for (int rq = 0; rq < 4; ++rq)                                             \
      _Pragma("unroll")                                                        \
      for (int h2 = 0; h2 < 2; ++h2)                                           \
        PPK[rq][h2] = pkrtz(p_[4 * rq + 2 * h2], p_[4 * rq + 2 * h2 + 1]);     \
  } while (0)

// PV of one half: k-slices KSB, KSB+1 (uses PPK of that half)
#define PV_HALF(PPK, KSB, CUR)                                                 \
  do {                                                                         \
    _Pragma("unroll")                                                          \
    for (int k1 = 0; k1 < 2; ++k1) {                                           \
      unsigned send0 = hi ? PPK[2 * k1][0]     : PPK[2 * k1 + 1][0];           \
      unsigned send1 = hi ? PPK[2 * k1][1]     : PPK[2 * k1 + 1][1];           \
      unsigned recv0 = (unsigned)__shfl_xor((int)send0, 32);                   \
      unsigned recv1 = (unsigned)__shfl_xor((int)send1, 32);                   \
      unsigned self0 = hi ? PPK[2 * k1 + 1][0] : PPK[2 * k1][0];               \
      unsigned self1 = hi ? PPK[2 * k1 + 1][1] : PPK[2 * k1][1];               \
      union { unsigned u[4]; half8 hv; } pf;                                   \
      pf.u[0] = hi ? recv0 : self0;                                            \
      pf.u[1] = hi ? recv1 : self1;                                            \
      pf.u[2] = hi ? self0 : recv0;                                            \
      pf.u[3] = hi ? self1 : recv1;                                            \
      __builtin_amdgcn_s_setprio(1);                                           \
      _Pragma("unroll")                                                        \
      for (int dt = 0; dt < 4; ++dt) {                                         \
        half8 vf = *(const half8*)(lds + voff[(KSB) + k1] +                    \
                    ((CUR) * 32768 + dt * 4096));                              \
        acc[dt] = __builtin_amdgcn_mfma_f32_32x32x16_f16(vf, pf.hv, acc[dt], 0, 0, 0); \
      }                                                                        \
      __builtin_amdgcn_s_setprio(0);                                           \
    }                                                                          \
  } while (0)

#define QK_HALF(S, JT, CUR)                                                    \
  do {                                                                         \
    _Pragma("unroll")                                                          \
    for (int r = 0; r < 16; ++r) (S)[r] = 0.f;                                 \
    __builtin_amdgcn_s_setprio(1);                                             \
    _Pragma("unroll")                                                          \
    for (int dk = 0; dk < 8; ++dk) {                                           \
      half8 kf = *(const half8*)(lds + koff[dk & 3] +                          \
                  ((CUR) * 32768 + (JT) * 8192 + (dk >> 2) * 128));            \
      (S) = __builtin_amdgcn_mfma_f32_32x32x16_f16(kf, qf[dk], (S), 0, 0, 0);  \
    }                                                                          \
    __builtin_amdgcn_s_setprio(0);                                             \
  } while (0)

#define TILE(CUR, T)                                                           \
  do {                                                                         \
    if ((T) + 1 < NT) STAGE((CUR) ^ 1, (T) + 1);                               \
    f32x16 sA, sB;                                                             \
    QK_HALF(sA, 0, CUR);                                                       \
    QK_HALF(sB, 1, CUR);                                                       \
    unsigned PA[4][2], PB[4][2];                                               \
    SM_HALF(sA, PA);          /* hides under QK_B chain drain */               \
    PV_HALF(PA, 0, CUR);                                                       \
    SM_HALF(sB, PB);          /* issues in PV_A's execution shadow */          \
    PV_HALF(PB, 2, CUR);                                                       \
    asm volatile("s_waitcnt vmcnt(0)");                                        \
    __syncthreads();                                                           \
  } while (0)

  STAGE(0, 0);
  asm volatile("s_waitcnt vmcnt(0)");
  __syncthreads();

  for (int t = 0; t < NT; t += 2) {
    TILE(0, t);
    TILE(1, t + 1);
  }
#undef TILE
#undef QK_HALF
#undef PV_HALF
#undef SM_HALF
#undef STAGE

  // epilogue: combine l across halves (disjoint j-sets), normalize, scatter by hmap
  float lt = lsum + __shfl_xor(lsum, 32);
  const float rl = 1.0f / lt;
  const int qrow = q0 + w * 32 + l31;
  const int srow = hmap[qrow];
  _Float16* ob = att + (size_t)srow * HID + h * HD;
#pragma unroll
  for (int dt = 0; dt < 4; ++dt)
#pragma unroll
    for (int rq = 0; rq < 4; ++rq) {
      const int d0 = dt * 32 + 8 * rq + 4 * hib;
      half4 o;
      o[0] = (_Float16)(acc[dt][4 * rq + 0] * rl);
      o[1] = (_Float16)(acc[dt][4 * rq + 1] * rl);
      o[2] = (_Float16)(acc[dt][4 * rq + 2] * rl);
      o[3] = (_Float16)(acc[dt][4 * rq + 3] * rl);
      *(half4*)(ob + d0) = o;
    }
}

extern "C" void kernel_launch(void* const* d_in, const int* in_sizes, int n_in,
                              void* d_out, int out_size, void* d_ws, size_t ws_size,
                              hipStream_t stream)
{
  const float* x     = (const float*)d_in[0];
  const float* w_qkv = (const float*)d_in[1];
  const float* w_out = (const float*)d_in[2];
  const int*   hmap  = (const int*)d_in[3];
  float* out = (float*)d_out;

  char* ws = (char*)d_ws;
  int* gidx = (int*)ws;                                          ws += 8192;
  _Float16* x16    = (_Float16*)ws;  // aliased with att16 (x16 dead after QKV GEMMs)
  _Float16* att16  = (_Float16*)ws;                              ws += (size_t)S_LEN * HID * 2;
  _Float16* wqkv16 = (_Float16*)ws;                              ws += (size_t)3 * HID * HID * 2;
  _Float16* wout16 = (_Float16*)ws;                              ws += (size_t)HID * HID * 2;
  _Float16* q16    = (_Float16*)ws;                              ws += (size_t)S_LEN * HID * 2;
  char* kimg  = ws;                                              ws += (size_t)NH * NT * 16384;
  char* vtimg = ws;

  k_build_idx<<<8, 256, 0, stream>>>(hmap, gidx);
  k_cvt_all<<<(NX8 + NW8 + NO8 + 255) / 256, 256, 0, stream>>>(x, w_qkv, w_out,
                                                               x16, wqkv16, wout16);

  // Q = x @ wq^T  (4096 x 2048)
  dim3 gq(HID / 128, S_LEN / 128);
  k_gemm2<0><<<gq, 256, 0, stream>>>(x16, wqkv16, q16, S_LEN, HID, HID, nullptr, nullptr, nullptr);
  // KV = x[gidx] @ wkv^T  (2048 x 4096) -> written directly as swizzled K/Vt images
  dim3 gkv(2 * HID / 128, NKV / 128);
  k_gemm2<2><<<gkv, 256, 0, stream>>>(x16, wqkv16 + (size_t)HID * HID, nullptr,
                                      NKV, 2 * HID, HID, gidx, kimg, vtimg);

  k_attn9<<<NH * (S_LEN / QBLK), 512, 65536, stream>>>(q16, kimg, vtimg, hmap, att16);

  // out = att @ w_out^T  (4096 x 2048, fp32)
  dim3 go(HID / 128, S_LEN / 128);
  k_gemm2<1><<<go, 256, 0, stream>>>(att16, wout16, out, S_LEN, HID, HID, nullptr, nullptr, nullptr);
}